// Round 1
// baseline (806.877 us; speedup 1.0000x reference)
//
#include <hip/hip_runtime.h>
#include <math.h>

// Problem constants (from reference):
//   features: (B=4, C=256, H=160, W=160) fp32
//   rois:     (N=512, 6) fp32  [bidx, cx, cy, h, w, theta]
//   output:   (N=512, C=256, PH=8, PW=64) fp32
#define RR_C  256
#define RR_H  160
#define RR_W  160
#define RR_PH 8
#define RR_PW 64
#define RR_N  512

// Block = 256 threads = (cc in [0,4)) x (px in [0,64)).
// One block per (n, py). Each thread computes geometry once, loops channels
// c = cc, cc+4, ... so the sin/cos/floor work is amortized across 64 channels.
// Lanes cover px -> output stores are 64 consecutive floats (256 B) per
// channel; corner loads across a wave lie on a short rotated line (cache
// friendly). OOB corners handled by zeroing the bilinear weight.
__global__ __launch_bounds__(256) void rroi_align_kernel(
    const float* __restrict__ features,
    const float* __restrict__ rois,
    float* __restrict__ out)
{
    const int blk = blockIdx.x;      // n * RR_PH + py
    const int n  = blk >> 3;
    const int py = blk & 7;
    const int px = threadIdx.x & 63;
    const int cc = threadIdx.x >> 6; // 0..3

    const float* r = rois + n * 6;
    const int   b     = (int)r[0];
    const float cx    = r[1];
    const float cy    = r[2];
    const float rh    = r[3];
    const float rw    = r[4];
    const float theta = r[5];

    const float sxs = rw * (1.0f / RR_PW);
    const float sys = rh * (1.0f / RR_PH);
    const float xx = ((float)px + 0.5f - RR_PW * 0.5f) * sxs;
    const float yy = ((float)py + 0.5f - RR_PH * 0.5f) * sys;

    const float ct = cosf(theta);
    const float st = sinf(theta);

    const float x = ct * xx + st * yy + cx;
    const float y = -st * xx + ct * yy + cy;

    const float x0f = floorf(x);
    const float y0f = floorf(y);
    const float lx = x - x0f;
    const float ly = y - y0f;

    const int x0i = (int)x0f;
    const int y0i = (int)y0f;
    const int x1i = x0i + 1;
    const int y1i = y0i + 1;

    const bool vx0 = (x0i >= 0) && (x0i < RR_W);
    const bool vx1 = (x1i >= 0) && (x1i < RR_W);
    const bool vy0 = (y0i >= 0) && (y0i < RR_H);
    const bool vy1 = (y1i >= 0) && (y1i < RR_H);

    const int cx0 = min(max(x0i, 0), RR_W - 1);
    const int cx1 = min(max(x1i, 0), RR_W - 1);
    const int cy0 = min(max(y0i, 0), RR_H - 1);
    const int cy1 = min(max(y1i, 0), RR_H - 1);

    // Fold validity into weights (value*0 == masked value; features finite).
    const float w00 = (1.0f - lx) * (1.0f - ly) * ((vx0 && vy0) ? 1.0f : 0.0f);
    const float w01 = lx          * (1.0f - ly) * ((vx1 && vy0) ? 1.0f : 0.0f);
    const float w10 = (1.0f - lx) * ly          * ((vx0 && vy1) ? 1.0f : 0.0f);
    const float w11 = lx          * ly          * ((vx1 && vy1) ? 1.0f : 0.0f);

    const int o00 = cy0 * RR_W + cx0;
    const int o01 = cy0 * RR_W + cx1;
    const int o10 = cy1 * RR_W + cx0;
    const int o11 = cy1 * RR_W + cx1;

    const size_t plane = (size_t)RR_H * RR_W;
    const float* base = features + (size_t)b * RR_C * plane + (size_t)cc * plane;
    float* op = out + (size_t)n * RR_C * (RR_PH * RR_PW)
                    + (size_t)cc * (RR_PH * RR_PW)
                    + (size_t)py * RR_PW + px;

    #pragma unroll 4
    for (int c = cc; c < RR_C; c += 4) {
        const float v00 = base[o00];
        const float v01 = base[o01];
        const float v10 = base[o10];
        const float v11 = base[o11];
        *op = w00 * v00 + w01 * v01 + w10 * v10 + w11 * v11;
        base += 4 * plane;
        op   += 4 * (RR_PH * RR_PW);
    }
}

extern "C" void kernel_launch(void* const* d_in, const int* in_sizes, int n_in,
                              void* d_out, int out_size, void* d_ws, size_t ws_size,
                              hipStream_t stream) {
    const float* features = (const float*)d_in[0];
    const float* rois     = (const float*)d_in[1];
    float* out = (float*)d_out;

    // One block per (n, py): 512*8 = 4096 blocks, 256 threads each.
    dim3 grid(RR_N * RR_PH);
    dim3 block(256);
    hipLaunchKernelGGL(rroi_align_kernel, grid, block, 0, stream,
                       features, rois, out);
}

// Round 2
// 575.373 us; speedup vs baseline: 1.4024x; 1.4024x over previous
//
#include <hip/hip_runtime.h>
#include <math.h>

// Problem constants (from reference):
//   features: (B=4, C=256, H=160, W=160) fp32
//   rois:     (N=512, 6) fp32  [bidx, cx, cy, h, w, theta]
//   output:   (N=512, C=256, PH=8, PW=64) fp32
#define RR_B  4
#define RR_C  256
#define RR_H  160
#define RR_W  160
#define RR_PH 8
#define RR_PW 64
#define RR_N  512
#define RR_HW (RR_H * RR_W)

// ---------------------------------------------------------------------------
// Kernel 1: transpose (B,C,H,W) -> (B,HW,C) into workspace.
// 64x64 tiles through LDS (pad +1 word -> conflict-free both phases).
// Both global read (along HW) and write (along C) are fully coalesced.
// Grid: B * (HW/64) * (C/64) = 4*400*4 = 6400 blocks, 256 threads.
// ---------------------------------------------------------------------------
__global__ __launch_bounds__(256) void transpose_kernel(
    const float* __restrict__ in,   // (B,C,HW)
    float* __restrict__ outT)       // (B,HW,C)
{
    __shared__ float tile[64][65];

    const int blk = blockIdx.x;
    const int b   = blk / 1600;
    const int rem = blk % 1600;
    const int hw0 = (rem >> 2) << 6;   // (rem/4)*64
    const int c0  = (rem & 3) << 6;    // (rem%4)*64

    const int tx = threadIdx.x & 63;
    const int ty = threadIdx.x >> 6;   // 0..3

    const float* src = in + ((size_t)b * RR_C) * RR_HW;
    float* dst = outT + ((size_t)b * RR_HW) * RR_C;

    #pragma unroll
    for (int i = 0; i < 16; ++i) {
        const int cl = i * 4 + ty;
        tile[cl][tx] = src[(size_t)(c0 + cl) * RR_HW + hw0 + tx];
    }
    __syncthreads();
    #pragma unroll
    for (int i = 0; i < 16; ++i) {
        const int hl = i * 4 + ty;
        dst[(size_t)(hw0 + hl) * RR_C + c0 + tx] = tile[tx][hl];
    }
}

// ---------------------------------------------------------------------------
// Kernel 2: gather from transposed features.
// One block per (n, py). threadIdx.x = pxg(2b) x lane(6b).
// lane -> 4 channels (float4), pxg -> which 16 of the 64 px.
// Each corner fetch is a coalesced dwordx4: 64 lanes x 16 B = 1 KB = all 256
// channels of one (y,x) pixel. 4x4 in-register transpose -> float4 output
// stores along px. Geometry is wave-uniform (scalarized by the compiler).
// ---------------------------------------------------------------------------
__global__ __launch_bounds__(256) void rroi_gather_kernel(
    const float* __restrict__ featT,  // (B,HW,C)
    const float* __restrict__ rois,
    float* __restrict__ out)          // (N,C,PH,PW)
{
    const int blk = blockIdx.x;       // n * RR_PH + py
    const int n   = blk >> 3;
    const int py  = blk & 7;
    const int lane = threadIdx.x & 63;
    const int pxg  = threadIdx.x >> 6;  // 0..3
    const int c0   = lane << 2;         // 4 channels per lane

    const float* r = rois + n * 6;
    const int   b     = (int)r[0];
    const float cx    = r[1];
    const float cy    = r[2];
    const float rh    = r[3];
    const float rw    = r[4];
    const float theta = r[5];

    const float sxs = rw * (1.0f / RR_PW);
    const float sys = rh * (1.0f / RR_PH);
    const float ct = cosf(theta);
    const float st = sinf(theta);
    const float yy = ((float)py + 0.5f - RR_PH * 0.5f) * sys;

    // x(px) = ct*(px+0.5-32)*sxs + st*yy + cx   (linear in px)
    const float xbase = ct * (0.5f - RR_PW * 0.5f) * sxs + st * yy + cx;
    const float xstep = ct * sxs;
    const float ybase = -st * (0.5f - RR_PW * 0.5f) * sxs + ct * yy + cy;
    const float ystep = -st * sxs;

    const float* fb = featT + (size_t)b * RR_HW * RR_C + c0;
    // out row start for channel c0, this (n, py):
    float* orow = out + ((size_t)n * RR_C + c0) * (RR_PH * RR_PW)
                      + (size_t)py * RR_PW;

    #pragma unroll
    for (int px4 = 0; px4 < 4; ++px4) {
        const int pxbase = pxg * 16 + px4 * 4;
        float4 v[4];  // v[k] = channels c0..c0+3 at px = pxbase+k
        #pragma unroll
        for (int k = 0; k < 4; ++k) {
            const int px = pxbase + k;
            const float x = xbase + (float)px * xstep;
            const float y = ybase + (float)px * ystep;
            const float x0f = floorf(x);
            const float y0f = floorf(y);
            const float lx = x - x0f;
            const float ly = y - y0f;
            const int x0i = (int)x0f;
            const int y0i = (int)y0f;
            const int x1i = x0i + 1;
            const int y1i = y0i + 1;
            const bool vx0 = (x0i >= 0) && (x0i < RR_W);
            const bool vx1 = (x1i >= 0) && (x1i < RR_W);
            const bool vy0 = (y0i >= 0) && (y0i < RR_H);
            const bool vy1 = (y1i >= 0) && (y1i < RR_H);
            const int cxi0 = min(max(x0i, 0), RR_W - 1);
            const int cxi1 = min(max(x1i, 0), RR_W - 1);
            const int cyi0 = min(max(y0i, 0), RR_H - 1);
            const int cyi1 = min(max(y1i, 0), RR_H - 1);
            const float w00 = (1.0f - lx) * (1.0f - ly) * ((vx0 && vy0) ? 1.0f : 0.0f);
            const float w01 = lx          * (1.0f - ly) * ((vx1 && vy0) ? 1.0f : 0.0f);
            const float w10 = (1.0f - lx) * ly          * ((vx0 && vy1) ? 1.0f : 0.0f);
            const float w11 = lx          * ly          * ((vx1 && vy1) ? 1.0f : 0.0f);

            const float4 v00 = *(const float4*)(fb + (size_t)(cyi0 * RR_W + cxi0) * RR_C);
            const float4 v01 = *(const float4*)(fb + (size_t)(cyi0 * RR_W + cxi1) * RR_C);
            const float4 v10 = *(const float4*)(fb + (size_t)(cyi1 * RR_W + cxi0) * RR_C);
            const float4 v11 = *(const float4*)(fb + (size_t)(cyi1 * RR_W + cxi1) * RR_C);

            v[k].x = w00 * v00.x + w01 * v01.x + w10 * v10.x + w11 * v11.x;
            v[k].y = w00 * v00.y + w01 * v01.y + w10 * v10.y + w11 * v11.y;
            v[k].z = w00 * v00.z + w01 * v01.z + w10 * v10.z + w11 * v11.z;
            v[k].w = w00 * v00.w + w01 * v01.w + w10 * v10.w + w11 * v11.w;
        }
        // 4x4 register transpose: one float4 store per channel row along px.
        float4 s0 = make_float4(v[0].x, v[1].x, v[2].x, v[3].x);
        float4 s1 = make_float4(v[0].y, v[1].y, v[2].y, v[3].y);
        float4 s2 = make_float4(v[0].z, v[1].z, v[2].z, v[3].z);
        float4 s3 = make_float4(v[0].w, v[1].w, v[2].w, v[3].w);
        *(float4*)(orow + 0 * (RR_PH * RR_PW) + pxbase) = s0;
        *(float4*)(orow + 1 * (RR_PH * RR_PW) + pxbase) = s1;
        *(float4*)(orow + 2 * (RR_PH * RR_PW) + pxbase) = s2;
        *(float4*)(orow + 3 * (RR_PH * RR_PW) + pxbase) = s3;
    }
}

// ---------------------------------------------------------------------------
// Fallback (R1 kernel): direct gather from (B,C,H,W). Used only if the
// workspace is too small for the transposed copy.
// ---------------------------------------------------------------------------
__global__ __launch_bounds__(256) void rroi_align_fallback(
    const float* __restrict__ features,
    const float* __restrict__ rois,
    float* __restrict__ out)
{
    const int blk = blockIdx.x;
    const int n  = blk >> 3;
    const int py = blk & 7;
    const int px = threadIdx.x & 63;
    const int cc = threadIdx.x >> 6;

    const float* r = rois + n * 6;
    const int   b     = (int)r[0];
    const float cx    = r[1];
    const float cy    = r[2];
    const float rh    = r[3];
    const float rw    = r[4];
    const float theta = r[5];

    const float sxs = rw * (1.0f / RR_PW);
    const float sys = rh * (1.0f / RR_PH);
    const float xx = ((float)px + 0.5f - RR_PW * 0.5f) * sxs;
    const float yy = ((float)py + 0.5f - RR_PH * 0.5f) * sys;
    const float ct = cosf(theta);
    const float st = sinf(theta);
    const float x = ct * xx + st * yy + cx;
    const float y = -st * xx + ct * yy + cy;
    const float x0f = floorf(x);
    const float y0f = floorf(y);
    const float lx = x - x0f;
    const float ly = y - y0f;
    const int x0i = (int)x0f;
    const int y0i = (int)y0f;
    const int x1i = x0i + 1;
    const int y1i = y0i + 1;
    const bool vx0 = (x0i >= 0) && (x0i < RR_W);
    const bool vx1 = (x1i >= 0) && (x1i < RR_W);
    const bool vy0 = (y0i >= 0) && (y0i < RR_H);
    const bool vy1 = (y1i >= 0) && (y1i < RR_H);
    const int cx0 = min(max(x0i, 0), RR_W - 1);
    const int cx1 = min(max(x1i, 0), RR_W - 1);
    const int cy0 = min(max(y0i, 0), RR_H - 1);
    const int cy1 = min(max(y1i, 0), RR_H - 1);
    const float w00 = (1.0f - lx) * (1.0f - ly) * ((vx0 && vy0) ? 1.0f : 0.0f);
    const float w01 = lx          * (1.0f - ly) * ((vx1 && vy0) ? 1.0f : 0.0f);
    const float w10 = (1.0f - lx) * ly          * ((vx0 && vy1) ? 1.0f : 0.0f);
    const float w11 = lx          * ly          * ((vx1 && vy1) ? 1.0f : 0.0f);
    const int o00 = cy0 * RR_W + cx0;
    const int o01 = cy0 * RR_W + cx1;
    const int o10 = cy1 * RR_W + cx0;
    const int o11 = cy1 * RR_W + cx1;
    const size_t plane = (size_t)RR_HW;
    const float* base = features + (size_t)b * RR_C * plane + (size_t)cc * plane;
    float* op = out + (size_t)n * RR_C * (RR_PH * RR_PW)
                    + (size_t)cc * (RR_PH * RR_PW)
                    + (size_t)py * RR_PW + px;
    #pragma unroll 4
    for (int c = cc; c < RR_C; c += 4) {
        const float v00 = base[o00];
        const float v01 = base[o01];
        const float v10 = base[o10];
        const float v11 = base[o11];
        *op = w00 * v00 + w01 * v01 + w10 * v10 + w11 * v11;
        base += 4 * plane;
        op   += 4 * (RR_PH * RR_PW);
    }
}

extern "C" void kernel_launch(void* const* d_in, const int* in_sizes, int n_in,
                              void* d_out, int out_size, void* d_ws, size_t ws_size,
                              hipStream_t stream) {
    const float* features = (const float*)d_in[0];
    const float* rois     = (const float*)d_in[1];
    float* out = (float*)d_out;

    const size_t needed = (size_t)RR_B * RR_HW * RR_C * sizeof(float); // 104.86 MB

    if (ws_size >= needed) {
        float* featT = (float*)d_ws;
        hipLaunchKernelGGL(transpose_kernel, dim3(RR_B * 400 * 4), dim3(256), 0,
                           stream, features, featT);
        hipLaunchKernelGGL(rroi_gather_kernel, dim3(RR_N * RR_PH), dim3(256), 0,
                           stream, featT, rois, out);
    } else {
        hipLaunchKernelGGL(rroi_align_fallback, dim3(RR_N * RR_PH), dim3(256), 0,
                           stream, features, rois, out);
    }
}

// Round 3
// 451.755 us; speedup vs baseline: 1.7861x; 1.2736x over previous
//
#include <hip/hip_runtime.h>
#include <math.h>

// Problem constants (from reference):
//   features: (B=4, C=256, H=160, W=160) fp32
//   rois:     (N=512, 6) fp32  [bidx, cx, cy, h, w, theta]
//   output:   (N=512, C=256, PH=8, PW=64) fp32
#define RR_B  4
#define RR_C  256
#define RR_H  160
#define RR_W  160
#define RR_PH 8
#define RR_PW 64
#define RR_N  512
#define RR_HW (RR_H * RR_W)

// ---------------------------------------------------------------------------
// Kernel 1: transpose (B,C,H,W) -> (B,HW,C) into workspace.
// 64x64 tiles through LDS (pad +1 word -> conflict-free both phases).
// ---------------------------------------------------------------------------
__global__ __launch_bounds__(256) void transpose_kernel(
    const float* __restrict__ in,   // (B,C,HW)
    float* __restrict__ outT)       // (B,HW,C)
{
    __shared__ float tile[64][65];

    const int blk = blockIdx.x;
    const int b   = blk / 1600;
    const int rem = blk % 1600;
    const int hw0 = (rem >> 2) << 6;
    const int c0  = (rem & 3) << 6;

    const int tx = threadIdx.x & 63;
    const int ty = threadIdx.x >> 6;

    const float* src = in + ((size_t)b * RR_C) * RR_HW;
    float* dst = outT + ((size_t)b * RR_HW) * RR_C;

    #pragma unroll
    for (int i = 0; i < 16; ++i) {
        const int cl = i * 4 + ty;
        tile[cl][tx] = src[(size_t)(c0 + cl) * RR_HW + hw0 + tx];
    }
    __syncthreads();
    #pragma unroll
    for (int i = 0; i < 16; ++i) {
        const int hl = i * 4 + ty;
        dst[(size_t)(hw0 + hl) * RR_C + c0 + tx] = tile[tx][hl];
    }
}

// ---------------------------------------------------------------------------
// Kernel 2: gather from transposed features, LDS-staged full-line stores.
// One block per (n, py). Compute phase: lane = channel-quad (c0 = 4*lane),
// pxg-wave covers px {pxg*4+k + 16*px4loc + 32*half}; each corner fetch is a
// coalesced 1 KB dwordx4 (all 256 channels of one pixel). 4x4 register
// transpose -> px-quad float4 per channel row -> XOR-swizzled LDS tile
// (256 ch x 32 px = 32 KB, two halves). Store phase: each wave writes
// 8 channels x 128 B fully contiguous -> every 64 B output line written
// exactly once, whole (kills the 2x write amplification + RMW fetches
// seen in R2: WRITE 537 MB, FETCH included 268 MB of output line fills).
// ---------------------------------------------------------------------------
__global__ __launch_bounds__(256) void rroi_gather_kernel(
    const float* __restrict__ featT,  // (B,HW,C)
    const float* __restrict__ rois,
    float* __restrict__ out)          // (N,C,PH,PW)
{
    __shared__ float4 tile4[256 * 8];   // 32 KB: [ch][q] q = local px-quad (swizzled)

    const int blk = blockIdx.x;       // n * RR_PH + py
    const int n   = blk >> 3;
    const int py  = blk & 7;
    const int tid  = threadIdx.x;
    const int lane = tid & 63;
    const int pxg  = tid >> 6;        // 0..3 (wave id)
    const int c0   = lane << 2;       // 4 channels per lane

    const float* r = rois + n * 6;
    const int   b     = (int)r[0];
    const float cx    = r[1];
    const float cy    = r[2];
    const float rh    = r[3];
    const float rw    = r[4];
    const float theta = r[5];

    const float sxs = rw * (1.0f / RR_PW);
    const float sys = rh * (1.0f / RR_PH);
    const float ct = cosf(theta);
    const float st = sinf(theta);
    const float yy = ((float)py + 0.5f - RR_PH * 0.5f) * sys;

    // x(px), y(px) are linear in px.
    const float xbase = ct * (0.5f - RR_PW * 0.5f) * sxs + st * yy + cx;
    const float xstep = ct * sxs;
    const float ybase = -st * (0.5f - RR_PW * 0.5f) * sxs + ct * yy + cy;
    const float ystep = -st * sxs;

    const float* fb = featT + (size_t)b * RR_HW * RR_C + c0;
    float* obase = out + ((size_t)n * RR_C) * (RR_PH * RR_PW)
                       + (size_t)py * RR_PW;

    #pragma unroll
    for (int half = 0; half < 2; ++half) {
        // ---- compute phase: this wave fills local px-quads q = px4loc*4+pxg
        #pragma unroll
        for (int px4loc = 0; px4loc < 2; ++px4loc) {
            const int q = px4loc * 4 + pxg;          // local px-quad, 0..7
            const int pxbase = half * 32 + q * 4;    // global px of element 0
            float4 v[4];
            #pragma unroll
            for (int k = 0; k < 4; ++k) {
                const int px = pxbase + k;
                const float x = xbase + (float)px * xstep;
                const float y = ybase + (float)px * ystep;
                const float x0f = floorf(x);
                const float y0f = floorf(y);
                const float lx = x - x0f;
                const float ly = y - y0f;
                const int x0i = (int)x0f;
                const int y0i = (int)y0f;
                const int x1i = x0i + 1;
                const int y1i = y0i + 1;
                const bool vx0 = (x0i >= 0) && (x0i < RR_W);
                const bool vx1 = (x1i >= 0) && (x1i < RR_W);
                const bool vy0 = (y0i >= 0) && (y0i < RR_H);
                const bool vy1 = (y1i >= 0) && (y1i < RR_H);
                const int cxi0 = min(max(x0i, 0), RR_W - 1);
                const int cxi1 = min(max(x1i, 0), RR_W - 1);
                const int cyi0 = min(max(y0i, 0), RR_H - 1);
                const int cyi1 = min(max(y1i, 0), RR_H - 1);
                const float w00 = (1.0f - lx) * (1.0f - ly) * ((vx0 && vy0) ? 1.0f : 0.0f);
                const float w01 = lx          * (1.0f - ly) * ((vx1 && vy0) ? 1.0f : 0.0f);
                const float w10 = (1.0f - lx) * ly          * ((vx0 && vy1) ? 1.0f : 0.0f);
                const float w11 = lx          * ly          * ((vx1 && vy1) ? 1.0f : 0.0f);

                const float4 v00 = *(const float4*)(fb + (size_t)(cyi0 * RR_W + cxi0) * RR_C);
                const float4 v01 = *(const float4*)(fb + (size_t)(cyi0 * RR_W + cxi1) * RR_C);
                const float4 v10 = *(const float4*)(fb + (size_t)(cyi1 * RR_W + cxi0) * RR_C);
                const float4 v11 = *(const float4*)(fb + (size_t)(cyi1 * RR_W + cxi1) * RR_C);

                v[k].x = w00 * v00.x + w01 * v01.x + w10 * v10.x + w11 * v11.x;
                v[k].y = w00 * v00.y + w01 * v01.y + w10 * v10.y + w11 * v11.y;
                v[k].z = w00 * v00.z + w01 * v01.z + w10 * v10.z + w11 * v11.z;
                v[k].w = w00 * v00.w + w01 * v01.w + w10 * v10.w + w11 * v11.w;
            }
            // 4x4 register transpose: s_j = px-quad vector for channel c0+j.
            const float4 s0 = make_float4(v[0].x, v[1].x, v[2].x, v[3].x);
            const float4 s1 = make_float4(v[0].y, v[1].y, v[2].y, v[3].y);
            const float4 s2 = make_float4(v[0].z, v[1].z, v[2].z, v[3].z);
            const float4 s3 = make_float4(v[0].w, v[1].w, v[2].w, v[3].w);
            // XOR swizzle on px-quad index: balanced bank-quads (8 lanes each).
            const int qs = q ^ (lane & 7);
            tile4[(c0 + 0) * 8 + qs] = s0;
            tile4[(c0 + 1) * 8 + qs] = s1;
            tile4[(c0 + 2) * 8 + qs] = s2;
            tile4[(c0 + 3) * 8 + qs] = s3;
        }
        __syncthreads();
        // ---- store phase: 8 iters; each wave instr = 8 channels x 128 B
        // contiguous -> full 64 B lines only.
        float* oh = obase + half * 32;
        #pragma unroll
        for (int it = 0; it < 8; ++it) {
            const int ch = it * 32 + (tid >> 3);
            const int q  = tid & 7;
            const int qs = q ^ ((ch >> 2) & 7);
            const float4 val = tile4[ch * 8 + qs];
            *(float4*)(oh + (size_t)ch * (RR_PH * RR_PW) + q * 4) = val;
        }
        __syncthreads();
    }
}

// ---------------------------------------------------------------------------
// Fallback (R1 kernel): direct gather from (B,C,H,W), if ws too small.
// ---------------------------------------------------------------------------
__global__ __launch_bounds__(256) void rroi_align_fallback(
    const float* __restrict__ features,
    const float* __restrict__ rois,
    float* __restrict__ out)
{
    const int blk = blockIdx.x;
    const int n  = blk >> 3;
    const int py = blk & 7;
    const int px = threadIdx.x & 63;
    const int cc = threadIdx.x >> 6;

    const float* r = rois + n * 6;
    const int   b     = (int)r[0];
    const float cx    = r[1];
    const float cy    = r[2];
    const float rh    = r[3];
    const float rw    = r[4];
    const float theta = r[5];

    const float sxs = rw * (1.0f / RR_PW);
    const float sys = rh * (1.0f / RR_PH);
    const float xx = ((float)px + 0.5f - RR_PW * 0.5f) * sxs;
    const float yy = ((float)py + 0.5f - RR_PH * 0.5f) * sys;
    const float ct = cosf(theta);
    const float st = sinf(theta);
    const float x = ct * xx + st * yy + cx;
    const float y = -st * xx + ct * yy + cy;
    const float x0f = floorf(x);
    const float y0f = floorf(y);
    const float lx = x - x0f;
    const float ly = y - y0f;
    const int x0i = (int)x0f;
    const int y0i = (int)y0f;
    const int x1i = x0i + 1;
    const int y1i = y0i + 1;
    const bool vx0 = (x0i >= 0) && (x0i < RR_W);
    const bool vx1 = (x1i >= 0) && (x1i < RR_W);
    const bool vy0 = (y0i >= 0) && (y0i < RR_H);
    const bool vy1 = (y1i >= 0) && (y1i < RR_H);
    const int cx0 = min(max(x0i, 0), RR_W - 1);
    const int cx1 = min(max(x1i, 0), RR_W - 1);
    const int cy0 = min(max(y0i, 0), RR_H - 1);
    const int cy1 = min(max(y1i, 0), RR_H - 1);
    const float w00 = (1.0f - lx) * (1.0f - ly) * ((vx0 && vy0) ? 1.0f : 0.0f);
    const float w01 = lx          * (1.0f - ly) * ((vx1 && vy0) ? 1.0f : 0.0f);
    const float w10 = (1.0f - lx) * ly          * ((vx0 && vy1) ? 1.0f : 0.0f);
    const float w11 = lx          * ly          * ((vx1 && vy1) ? 1.0f : 0.0f);
    const int o00 = cy0 * RR_W + cx0;
    const int o01 = cy0 * RR_W + cx1;
    const int o10 = cy1 * RR_W + cx0;
    const int o11 = cy1 * RR_W + cx1;
    const size_t plane = (size_t)RR_HW;
    const float* base = features + (size_t)b * RR_C * plane + (size_t)cc * plane;
    float* op = out + (size_t)n * RR_C * (RR_PH * RR_PW)
                    + (size_t)cc * (RR_PH * RR_PW)
                    + (size_t)py * RR_PW + px;
    #pragma unroll 4
    for (int c = cc; c < RR_C; c += 4) {
        const float v00 = base[o00];
        const float v01 = base[o01];
        const float v10 = base[o10];
        const float v11 = base[o11];
        *op = w00 * v00 + w01 * v01 + w10 * v10 + w11 * v11;
        base += 4 * plane;
        op   += 4 * (RR_PH * RR_PW);
    }
}

extern "C" void kernel_launch(void* const* d_in, const int* in_sizes, int n_in,
                              void* d_out, int out_size, void* d_ws, size_t ws_size,
                              hipStream_t stream) {
    const float* features = (const float*)d_in[0];
    const float* rois     = (const float*)d_in[1];
    float* out = (float*)d_out;

    const size_t needed = (size_t)RR_B * RR_HW * RR_C * sizeof(float); // 104.86 MB

    if (ws_size >= needed) {
        float* featT = (float*)d_ws;
        hipLaunchKernelGGL(transpose_kernel, dim3(RR_B * 400 * 4), dim3(256), 0,
                           stream, features, featT);
        hipLaunchKernelGGL(rroi_gather_kernel, dim3(RR_N * RR_PH), dim3(256), 0,
                           stream, featT, rois, out);
    } else {
        hipLaunchKernelGGL(rroi_align_fallback, dim3(RR_N * RR_PH), dim3(256), 0,
                           stream, features, rois, out);
    }
}